// Round 17
// baseline (47.596 us; speedup 1.0000x reference)
//
#include <hip/hip_runtime.h>

#define H 1024
#define W 1024
#define OH 1016
#define OW 1016
#define BAND 64            // output rows per sweep; 16*64 = 1024 exact
#define STEPS (BAND + 8)   // 72 input rows swept
#define WCOLS 248          // useful output cols per 64-lane wave
#define NWX 5              // ceil(1016 / 248)
#define NBANDS 16
#define NPAIR 8            // image pairs: (z, z+8)

typedef float vfloat4 __attribute__((ext_vector_type(4)));

__global__ __launch_bounds__(64)
void cov_kernel(const float* __restrict__ xg,
                const float* __restrict__ yg,
                float* __restrict__ outg) {
    const int t    = threadIdx.x;                  // lane 0..63
    const int wx   = blockIdx.x;                   // column group
    const int band = blockIdx.y;                   // row band 0..15
    const int imgp = blockIdx.z;                   // image pair base 0..7

    const int cb  = wx * WCOLS + 4 * t;            // lane's first (logical) column
    const int cbl = min(cb, W - 4);                // clamped load column (branch-free)
    const int O   = band * BAND;                   // first output row of band
    const bool sok = (t <= 61) && (cb <= OW - 4);

    const float* xb[2] = { xg + (size_t)imgp * H * W,       xg + (size_t)(imgp + 8) * H * W };
    const float* yb[2] = { yg + (size_t)imgp * H * W,       yg + (size_t)(imgp + 8) * H * W };
    float*       ob[2] = { outg + (size_t)imgp * OH * OW,   outg + (size_t)(imgp + 8) * OH * OW };

    const float4 z4 = make_float4(0.f, 0.f, 0.f, 0.f);
    float4 hx[2][5], hy[2][5], hp[2][5];
    #pragma unroll
    for (int q = 0; q < 2; ++q)
        #pragma unroll
        for (int i = 0; i < 5; ++i) { hx[q][i] = z4; hy[q][i] = z4; hp[q][i] = z4; }
    float4 csx[2] = { z4, z4 }, csy[2] = { z4, z4 }, ps[2] = { z4, z4 };
    const float k = 1.0f / 25.0f;

    float4 pnx[2][2], pny[2][2];

    // unconditional clamped load: row min(R,1023), col cbl — always in bounds
#define LOAD_ROW(Q, R, PF)                                                     \
    {                                                                          \
        const int _r = min((int)(R), H - 1);                                   \
        pnx[Q][PF] = *reinterpret_cast<const float4*>(xb[Q] + (size_t)_r * W + cbl); \
        pny[Q][PF] = *reinterpret_cast<const float4*>(yb[Q] + (size_t)_r * W + cbl); \
    }

#define PUSH_ROW(Q, NX, NY, PH)                                                \
    {                                                                          \
        csx[Q].x += (NX).x - hx[Q][PH].x; csx[Q].y += (NX).y - hx[Q][PH].y;    \
        csx[Q].z += (NX).z - hx[Q][PH].z; csx[Q].w += (NX).w - hx[Q][PH].w;    \
        csy[Q].x += (NY).x - hy[Q][PH].x; csy[Q].y += (NY).y - hy[Q][PH].y;    \
        csy[Q].z += (NY).z - hy[Q][PH].z; csy[Q].w += (NY).w - hy[Q][PH].w;    \
        hx[Q][PH] = (NX); hy[Q][PH] = (NY);                                    \
    }

#define PROD_ROW(Q, PC, PP)                                                    \
    {                                                                          \
        float bx0 = __shfl_down(csx[Q].x, 1), bx1 = __shfl_down(csx[Q].y, 1);  \
        float bx2 = __shfl_down(csx[Q].z, 1), bx3 = __shfl_down(csx[Q].w, 1);  \
        float by0 = __shfl_down(csy[Q].x, 1), by1 = __shfl_down(csy[Q].y, 1);  \
        float by2 = __shfl_down(csy[Q].z, 1), by3 = __shfl_down(csy[Q].w, 1);  \
        float cx2 = __shfl_down(hx[Q][PC].x, 1), cx3 = __shfl_down(hx[Q][PC].y, 1); \
        float cy2 = __shfl_down(hy[Q][PC].x, 1), cy3 = __shfl_down(hy[Q][PC].y, 1); \
        float sx0 = csx[Q].x + csx[Q].y + csx[Q].z + csx[Q].w + bx0;           \
        float sx1 = sx0 - csx[Q].x + bx1;                                      \
        float sx2 = sx1 - csx[Q].y + bx2;                                      \
        float sx3 = sx2 - csx[Q].z + bx3;                                      \
        float sy0 = csy[Q].x + csy[Q].y + csy[Q].z + csy[Q].w + by0;           \
        float sy1 = sy0 - csy[Q].x + by1;                                      \
        float sy2 = sy1 - csy[Q].y + by2;                                      \
        float sy3 = sy2 - csy[Q].z + by3;                                      \
        float4 p;                                                              \
        p.x = (hx[Q][PC].z - sx0 * k) * (hy[Q][PC].z - sy0 * k);               \
        p.y = (hx[Q][PC].w - sx1 * k) * (hy[Q][PC].w - sy1 * k);               \
        p.z = (cx2         - sx2 * k) * (cy2         - sy2 * k);               \
        p.w = (cx3         - sx3 * k) * (cy3         - sy3 * k);               \
        ps[Q].x += p.x - hp[Q][PP].x; ps[Q].y += p.y - hp[Q][PP].y;            \
        ps[Q].z += p.z - hp[Q][PP].z; ps[Q].w += p.w - hp[Q][PP].w;            \
        hp[Q][PP] = p;                                                         \
    }

#define OUT_ROW(Q, O_ROW)                                                      \
    {                                                                          \
        float bp0 = __shfl_down(ps[Q].x, 1), bp1 = __shfl_down(ps[Q].y, 1);    \
        float bp2 = __shfl_down(ps[Q].z, 1), bp3 = __shfl_down(ps[Q].w, 1);    \
        float s0 = ps[Q].x + ps[Q].y + ps[Q].z + ps[Q].w + bp0;                \
        float s1 = s0 - ps[Q].x + bp1;                                         \
        float s2 = s1 - ps[Q].y + bp2;                                         \
        float s3 = s2 - ps[Q].z + bp3;                                         \
        if (sok && (O_ROW) < OH) {                                             \
            vfloat4 ov = { s0 * k, s1 * k, s2 * k, s3 * k };                   \
            __builtin_nontemporal_store(ov,                                    \
                reinterpret_cast<vfloat4*>(ob[Q] + (size_t)(O_ROW) * OW + cb)); \
        }                                                                      \
    }

    // ---- prime prefetch: rows O, O+1, both streams ----
    LOAD_ROW(0, O + 0, 0); LOAD_ROW(1, O + 0, 0);
    LOAD_ROW(0, O + 1, 1); LOAD_ROW(1, O + 1, 1);

    // ---- prologue: s = 0..7 (no outputs) ----
    #pragma unroll
    for (int j = 0; j < 8; ++j) {
        const int pf = j % 2;
        const int ph = j % 5;
        const float4 nxA = pnx[0][pf], nyA = pny[0][pf];
        const float4 nxB = pnx[1][pf], nyB = pny[1][pf];
        LOAD_ROW(0, O + j + 2, pf);
        LOAD_ROW(1, O + j + 2, pf);
        PUSH_ROW(0, nxA, nyA, ph);
        PUSH_ROW(1, nxB, nyB, ph);
        if (j >= 4) {
            PROD_ROW(0, ((j % 5) + 3) % 5, (j + 1) % 5);
            PROD_ROW(1, ((j % 5) + 3) % 5, (j + 1) % 5);
        }
    }

    // ---- main: s = 8..67, rolled with unroll-10 (ss ≡ 8 mod 10) ----
    for (int ss = 8; ss < 68; ss += 10) {
        #pragma unroll
        for (int j = 0; j < 10; ++j) {
            const int ph = (8 + j) % 5;
            const int pc = (ph + 3) % 5;
            const int pp = (8 + j + 1) % 5;
            const int pf = j % 2;
            const int s  = ss + j;
            const float4 nxA = pnx[0][pf], nyA = pny[0][pf];
            const float4 nxB = pnx[1][pf], nyB = pny[1][pf];
            if (s + 2 < STEPS) { LOAD_ROW(0, O + s + 2, pf); LOAD_ROW(1, O + s + 2, pf); }
            PUSH_ROW(0, nxA, nyA, ph);
            PROD_ROW(0, pc, pp);
            OUT_ROW(0, O + s - 8);
            PUSH_ROW(1, nxB, nyB, ph);
            PROD_ROW(1, pc, pp);
            OUT_ROW(1, O + s - 8);
        }
    }

    // ---- tail: s = 68..71 (loads rows 70,71 at s=68,69) ----
    #pragma unroll
    for (int j = 0; j < 4; ++j) {
        const int s  = 68 + j;
        const int ph = (68 + j) % 5;
        const int pc = (ph + 3) % 5;
        const int pp = (68 + j + 1) % 5;
        const int pf = j % 2;
        const float4 nxA = pnx[0][pf], nyA = pny[0][pf];
        const float4 nxB = pnx[1][pf], nyB = pny[1][pf];
        if (s + 2 < STEPS) { LOAD_ROW(0, O + s + 2, pf); LOAD_ROW(1, O + s + 2, pf); }
        PUSH_ROW(0, nxA, nyA, ph);
        PROD_ROW(0, pc, pp);
        OUT_ROW(0, O + s - 8);
        PUSH_ROW(1, nxB, nyB, ph);
        PROD_ROW(1, pc, pp);
        OUT_ROW(1, O + s - 8);
    }
}

extern "C" void kernel_launch(void* const* d_in, const int* in_sizes, int n_in,
                              void* d_out, int out_size, void* d_ws, size_t ws_size,
                              hipStream_t stream) {
    const float* x = (const float*)d_in[0];
    const float* y = (const float*)d_in[1];
    float* out = (float*)d_out;

    dim3 grid(NWX, NBANDS, NPAIR);   // 5 x 16 x 8 = 640 blocks, 2 images each
    dim3 block(64);
    cov_kernel<<<grid, block, 0, stream>>>(x, y, out);
}

// Round 19
// 43.756 us; speedup vs baseline: 1.0877x; 1.0877x over previous
//
#include <hip/hip_runtime.h>

#define H 1024
#define W 1024
#define OH 1016
#define OW 1016
#define NB 16
#define BAND 64            // output rows per wave; 16*64 = 1024 exact
#define STEPS (BAND + 8)   // 72 input rows swept per wave
#define WCOLS 248          // useful output cols per 64-lane wave
#define NWX 5              // ceil(1016 / 248)
#define NBANDS 16
#define PFD 4              // prefetch depth (row-pairs in flight)

typedef float vfloat4 __attribute__((ext_vector_type(4)));

__global__ __launch_bounds__(64)
void cov_kernel(const float* __restrict__ xg,
                const float* __restrict__ yg,
                float* __restrict__ outg) {
    const int t    = threadIdx.x;                  // lane 0..63
    const int wx   = blockIdx.x;                   // column group
    const int band = blockIdx.y;                   // row band 0..15
    const int img  = blockIdx.z;

    const int cb = wx * WCOLS + 4 * t;             // lane's first column
    const int O  = band * BAND;                    // first output row of band
    const bool lok = (cb <= W - 4);
    const bool sok = (t <= 61) && (cb <= OW - 4);

    const float* xb = xg + (size_t)img * H * W;
    const float* yb = yg + (size_t)img * H * W;
    float* ob = outg + (size_t)img * OH * OW;

    const float4 z4 = make_float4(0.f, 0.f, 0.f, 0.f);
    float4 hx[5], hy[5], hp[5];
    #pragma unroll
    for (int i = 0; i < 5; ++i) { hx[i] = z4; hy[i] = z4; hp[i] = z4; }
    float4 csx = z4, csy = z4, ps = z4;
    const float k = 1.0f / 25.0f;

    float4 pnx[PFD], pny[PFD];

#define LOAD_ROW(R, VX, VY)                                                    \
    {                                                                          \
        float4 _vx = z4, _vy = z4;                                             \
        if (lok && (R) < H) {                                                  \
            _vx = *reinterpret_cast<const float4*>(xb + (size_t)(R) * W + cb); \
            _vy = *reinterpret_cast<const float4*>(yb + (size_t)(R) * W + cb); \
        }                                                                      \
        VX = _vx; VY = _vy;                                                    \
    }

#define PUSH_ROW(NX, NY, PH)                                                   \
    {                                                                          \
        csx.x += (NX).x - hx[PH].x; csx.y += (NX).y - hx[PH].y;                \
        csx.z += (NX).z - hx[PH].z; csx.w += (NX).w - hx[PH].w;                \
        csy.x += (NY).x - hy[PH].x; csy.y += (NY).y - hy[PH].y;                \
        csy.z += (NY).z - hy[PH].z; csy.w += (NY).w - hy[PH].w;                \
        hx[PH] = (NX); hy[PH] = (NY);                                          \
    }

// balanced-tree 5-window sums, prefix P uniquifies temporaries per expansion
#define HSUM5(P, S0, S1, S2, S3, C, B0, B1, B2, B3)                            \
    float P##t01 = (C).x + (C).y, P##t23 = (C).z + (C).w;                      \
    float P##tyz = (C).y + (C).z, P##twb = (C).w + (B0);                       \
    float P##tb01 = (B0) + (B1), P##tb23 = (B2) + (B3);                        \
    float S0 = (P##t01 + P##t23) + (B0);                                       \
    float S1 = (P##tyz + P##twb) + (B1);                                       \
    float S2 = (P##t23 + P##tb01) + (B2);                                      \
    float S3 = (P##twb + (B1)) + P##tb23;

#define PROD_ROW(PC, PP)                                                       \
    {                                                                          \
        float bx0 = __shfl_down(csx.x, 1), bx1 = __shfl_down(csx.y, 1);        \
        float bx2 = __shfl_down(csx.z, 1), bx3 = __shfl_down(csx.w, 1);        \
        float by0 = __shfl_down(csy.x, 1), by1 = __shfl_down(csy.y, 1);        \
        float by2 = __shfl_down(csy.z, 1), by3 = __shfl_down(csy.w, 1);        \
        float cx2 = __shfl_down(hx[PC].x, 1), cx3 = __shfl_down(hx[PC].y, 1);  \
        float cy2 = __shfl_down(hy[PC].x, 1), cy3 = __shfl_down(hy[PC].y, 1);  \
        { HSUM5(_x, sx0, sx1, sx2, sx3, csx, bx0, bx1, bx2, bx3)               \
          HSUM5(_y, sy0, sy1, sy2, sy3, csy, by0, by1, by2, by3)               \
          float4 p;                                                            \
          p.x = (hx[PC].z - sx0 * k) * (hy[PC].z - sy0 * k);                   \
          p.y = (hx[PC].w - sx1 * k) * (hy[PC].w - sy1 * k);                   \
          p.z = (cx2       - sx2 * k) * (cy2       - sy2 * k);                 \
          p.w = (cx3       - sx3 * k) * (cy3       - sy3 * k);                 \
          ps.x += p.x - hp[PP].x; ps.y += p.y - hp[PP].y;                      \
          ps.z += p.z - hp[PP].z; ps.w += p.w - hp[PP].w;                      \
          hp[PP] = p; }                                                        \
    }

#define OUT_ROW(O_ROW)                                                         \
    {                                                                          \
        float bp0 = __shfl_down(ps.x, 1), bp1 = __shfl_down(ps.y, 1);          \
        float bp2 = __shfl_down(ps.z, 1), bp3 = __shfl_down(ps.w, 1);          \
        HSUM5(_o, s0, s1, s2, s3, ps, bp0, bp1, bp2, bp3)                      \
        if (sok && (O_ROW) < OH) {                                             \
            vfloat4 ov = { s0 * k, s1 * k, s2 * k, s3 * k };                   \
            __builtin_nontemporal_store(ov,                                    \
                reinterpret_cast<vfloat4*>(ob + (size_t)(O_ROW) * OW + cb));   \
        }                                                                      \
    }

    // ---- prime prefetch: rows O..O+3 into slots 0..3 ----
    LOAD_ROW(O + 0, pnx[0], pny[0]);
    LOAD_ROW(O + 1, pnx[1], pny[1]);
    LOAD_ROW(O + 2, pnx[2], pny[2]);
    LOAD_ROW(O + 3, pnx[3], pny[3]);

    // ---- prologue: s = 0..7 (no outputs) ----
    #pragma unroll
    for (int j = 0; j < 8; ++j) {
        const int pf = j % 4;
        const float4 nx = pnx[pf], ny = pny[pf];
        LOAD_ROW(O + j + 4, pnx[pf], pny[pf]);     // j+4 <= 11 < STEPS
        PUSH_ROW(nx, ny, j % 5);
        if (j >= 4) PROD_ROW(((j % 5) + 3) % 5, (j + 1) % 5);
    }

    // ---- main: s = 8..67, rolled with unroll-20 (lcm(5,4); ss ≡ 8 mod 20) ----
    for (int ss = 8; ss < 68; ss += 20) {
        #pragma unroll
        for (int j = 0; j < 20; ++j) {
            // actual s = ss + j; ss ≡ 8 (mod 20): s%5 = (8+j)%5, s%4 = j%4
            const int ph = (8 + j) % 5;
            const int pc = (ph + 3) % 5;
            const int pp = (8 + j + 1) % 5;
            const int pf = j % 4;                  // 8%4 == 0
            const int s  = ss + j;                 // max 67 -> loads row 71 max
            const float4 nx = pnx[pf], ny = pny[pf];
            LOAD_ROW(O + s + 4, pnx[pf], pny[pf]); // s+4 <= 71 < STEPS always
            PUSH_ROW(nx, ny, ph);
            PROD_ROW(pc, pp);
            OUT_ROW(O + s - 8);
        }
    }

    // ---- tail: s = 68..71 (rows 68..71 already in flight; no more loads) ----
    #pragma unroll
    for (int j = 0; j < 4; ++j) {
        const int s  = 68 + j;
        const int ph = (68 + j) % 5;               // = (3+j)%5
        const int pc = (ph + 3) % 5;
        const int pp = (68 + j + 1) % 5;
        const int pf = j % 4;                      // 68%4 == 0
        const float4 nx = pnx[pf], ny = pny[pf];
        PUSH_ROW(nx, ny, ph);
        PROD_ROW(pc, pp);
        OUT_ROW(O + s - 8);
    }
}

extern "C" void kernel_launch(void* const* d_in, const int* in_sizes, int n_in,
                              void* d_out, int out_size, void* d_ws, size_t ws_size,
                              hipStream_t stream) {
    const float* x = (const float*)d_in[0];
    const float* y = (const float*)d_in[1];
    float* out = (float*)d_out;

    dim3 grid(NWX, NBANDS, NB);     // 5 x 16 x 16 = 1280 one-wave blocks = 5/CU exact
    dim3 block(64);
    cov_kernel<<<grid, block, 0, stream>>>(x, y, out);
}

// Round 20
// 41.289 us; speedup vs baseline: 1.1527x; 1.0598x over previous
//
#include <hip/hip_runtime.h>

#define H 1024
#define W 1024
#define OH 1016
#define OW 1016
#define NB 16
#define BAND 64            // output rows per wave; 16*64 = 1024 exact
#define STEPS (BAND + 8)   // 72 input rows swept per wave
#define WCOLS 248          // useful output cols per 64-lane wave
#define NWX 5              // ceil(1016 / 248)
#define NBANDS 16
#define PFD 4              // prefetch depth (row-pairs in flight)

__global__ __launch_bounds__(64)
void cov_kernel(const float* __restrict__ xg,
                const float* __restrict__ yg,
                float* __restrict__ outg) {
    const int t    = threadIdx.x;                  // lane 0..63
    const int wx   = blockIdx.x;                   // column group
    const int band = blockIdx.y;                   // row band 0..15
    const int img  = blockIdx.z;

    const int cb = wx * WCOLS + 4 * t;             // lane's first column
    const int O  = band * BAND;                    // first output row of band
    const bool lok = (cb <= W - 4);
    const bool sok = (t <= 61) && (cb <= OW - 4);

    const float* xb = xg + (size_t)img * H * W;
    const float* yb = yg + (size_t)img * H * W;
    float* ob = outg + (size_t)img * OH * OW;

    const float4 z4 = make_float4(0.f, 0.f, 0.f, 0.f);
    float4 hx[5], hy[5], hp[5];
    #pragma unroll
    for (int i = 0; i < 5; ++i) { hx[i] = z4; hy[i] = z4; hp[i] = z4; }
    float4 csx = z4, csy = z4, ps = z4;
    const float k = 1.0f / 25.0f;

    float4 pnx[PFD], pny[PFD];

#define LOAD_ROW(R, VX, VY)                                                    \
    {                                                                          \
        float4 _vx = z4, _vy = z4;                                             \
        if (lok && (R) < H) {                                                  \
            _vx = *reinterpret_cast<const float4*>(xb + (size_t)(R) * W + cb); \
            _vy = *reinterpret_cast<const float4*>(yb + (size_t)(R) * W + cb); \
        }                                                                      \
        VX = _vx; VY = _vy;                                                    \
    }

#define PUSH_ROW(NX, NY, PH)                                                   \
    {                                                                          \
        csx.x += (NX).x - hx[PH].x; csx.y += (NX).y - hx[PH].y;                \
        csx.z += (NX).z - hx[PH].z; csx.w += (NX).w - hx[PH].w;                \
        csy.x += (NY).x - hy[PH].x; csy.y += (NY).y - hy[PH].y;                \
        csy.z += (NY).z - hy[PH].z; csy.w += (NY).w - hy[PH].w;                \
        hx[PH] = (NX); hy[PH] = (NY);                                          \
    }

#define PROD_ROW(PC, PP)                                                       \
    {                                                                          \
        float bx0 = __shfl_down(csx.x, 1), bx1 = __shfl_down(csx.y, 1);        \
        float bx2 = __shfl_down(csx.z, 1), bx3 = __shfl_down(csx.w, 1);        \
        float by0 = __shfl_down(csy.x, 1), by1 = __shfl_down(csy.y, 1);        \
        float by2 = __shfl_down(csy.z, 1), by3 = __shfl_down(csy.w, 1);        \
        float cx2 = __shfl_down(hx[PC].x, 1), cx3 = __shfl_down(hx[PC].y, 1);  \
        float cy2 = __shfl_down(hy[PC].x, 1), cy3 = __shfl_down(hy[PC].y, 1);  \
        float sx0 = csx.x + csx.y + csx.z + csx.w + bx0;                       \
        float sx1 = sx0 - csx.x + bx1;                                         \
        float sx2 = sx1 - csx.y + bx2;                                         \
        float sx3 = sx2 - csx.z + bx3;                                         \
        float sy0 = csy.x + csy.y + csy.z + csy.w + by0;                       \
        float sy1 = sy0 - csy.x + by1;                                         \
        float sy2 = sy1 - csy.y + by2;                                         \
        float sy3 = sy2 - csy.z + by3;                                         \
        float4 p;                                                              \
        p.x = (hx[PC].z - sx0 * k) * (hy[PC].z - sy0 * k);                     \
        p.y = (hx[PC].w - sx1 * k) * (hy[PC].w - sy1 * k);                     \
        p.z = (cx2       - sx2 * k) * (cy2       - sy2 * k);                   \
        p.w = (cx3       - sx3 * k) * (cy3       - sy3 * k);                   \
        ps.x += p.x - hp[PP].x; ps.y += p.y - hp[PP].y;                        \
        ps.z += p.z - hp[PP].z; ps.w += p.w - hp[PP].w;                        \
        hp[PP] = p;                                                            \
    }

#define OUT_ROW(O_ROW)                                                         \
    {                                                                          \
        float bp0 = __shfl_down(ps.x, 1), bp1 = __shfl_down(ps.y, 1);          \
        float bp2 = __shfl_down(ps.z, 1), bp3 = __shfl_down(ps.w, 1);          \
        float s0 = ps.x + ps.y + ps.z + ps.w + bp0;                            \
        float s1 = s0 - ps.x + bp1;                                            \
        float s2 = s1 - ps.y + bp2;                                            \
        float s3 = s2 - ps.z + bp3;                                            \
        if (sok && (O_ROW) < OH) {                                             \
            float4 ov = make_float4(s0 * k, s1 * k, s2 * k, s3 * k);           \
            *reinterpret_cast<float4*>(ob + (size_t)(O_ROW) * OW + cb) = ov;   \
        }                                                                      \
    }

    // ---- prime prefetch: rows O..O+3 into slots 0..3 ----
    LOAD_ROW(O + 0, pnx[0], pny[0]);
    LOAD_ROW(O + 1, pnx[1], pny[1]);
    LOAD_ROW(O + 2, pnx[2], pny[2]);
    LOAD_ROW(O + 3, pnx[3], pny[3]);

    // ---- prologue: s = 0..7 (no outputs) ----
    #pragma unroll
    for (int j = 0; j < 8; ++j) {
        const int pf = j % 4;
        const float4 nx = pnx[pf], ny = pny[pf];
        LOAD_ROW(O + j + 4, pnx[pf], pny[pf]);     // j+4 <= 11 < STEPS
        PUSH_ROW(nx, ny, j % 5);
        if (j >= 4) PROD_ROW(((j % 5) + 3) % 5, (j + 1) % 5);
    }

    // ---- main: s = 8..67, rolled with unroll-20 (lcm(5,4); ss ≡ 8 mod 20) ----
    for (int ss = 8; ss < 68; ss += 20) {
        #pragma unroll
        for (int j = 0; j < 20; ++j) {
            // actual s = ss + j; ss ≡ 8 (mod 20): s%5 = (8+j)%5, s%4 = j%4
            const int ph = (8 + j) % 5;
            const int pc = (ph + 3) % 5;
            const int pp = (8 + j + 1) % 5;
            const int pf = j % 4;                  // 8%4 == 0
            const int s  = ss + j;                 // max 67 -> loads row 71 max
            const float4 nx = pnx[pf], ny = pny[pf];
            LOAD_ROW(O + s + 4, pnx[pf], pny[pf]); // s+4 <= 71 < STEPS always
            PUSH_ROW(nx, ny, ph);
            PROD_ROW(pc, pp);
            OUT_ROW(O + s - 8);
        }
    }

    // ---- tail: s = 68..71 (rows 68..71 already in flight; no more loads) ----
    #pragma unroll
    for (int j = 0; j < 4; ++j) {
        const int s  = 68 + j;
        const int ph = (68 + j) % 5;               // = (3+j)%5
        const int pc = (ph + 3) % 5;
        const int pp = (68 + j + 1) % 5;
        const int pf = j % 4;                      // 68%4 == 0
        const float4 nx = pnx[pf], ny = pny[pf];
        PUSH_ROW(nx, ny, ph);
        PROD_ROW(pc, pp);
        OUT_ROW(O + s - 8);
    }
}

extern "C" void kernel_launch(void* const* d_in, const int* in_sizes, int n_in,
                              void* d_out, int out_size, void* d_ws, size_t ws_size,
                              hipStream_t stream) {
    const float* x = (const float*)d_in[0];
    const float* y = (const float*)d_in[1];
    float* out = (float*)d_out;

    dim3 grid(NWX, NBANDS, NB);     // 5 x 16 x 16 = 1280 one-wave blocks = 5/CU exact
    dim3 block(64);
    cov_kernel<<<grid, block, 0, stream>>>(x, y, out);
}